// Round 4
// baseline (137.515 us; speedup 1.0000x reference)
//
#include <hip/hip_runtime.h>

typedef unsigned int u32;
typedef unsigned short u16;
typedef float f32x4 __attribute__((ext_vector_type(4)));
typedef u32 u32x4 __attribute__((ext_vector_type(4)));
typedef u32 u32x2 __attribute__((ext_vector_type(2)));

// ---------- helpers ----------
__device__ __forceinline__ u16 f2bf(float f) {
    u32 u = __builtin_bit_cast(u32, f);
    u = (u + 0x7FFFu + ((u >> 16) & 1u)) >> 16;   // RNE
    return (u16)u;
}

// v_mfma_f32_16x16x32_bf16. A-frag: lane holds A[l&15][8*(l>>4)+j];
// B-frag: B[8*(l>>4)+j][l&15]; C/D: col=l&15, row=(l>>4)*4+reg.
__device__ __forceinline__ void mfma16(f32x4& d, const u32x4& a, const u32x4& b) {
    asm("v_mfma_f32_16x16x32_bf16 %0, %1, %2, %0" : "+v"(d) : "v"(a), "v"(b));
}

// single exp2 (cold path)
__device__ __forceinline__ float exp2a(float x) {
    float r;
    asm("v_exp_f32 %0, %1\n\ts_nop 1" : "=v"(r) : "v"(x));
    return r;
}
// batched exp2: 4 independent v_exp_f32, one trailing hazard nop
// (last op has identical spacing to exp2a: s_nop 1 before any consumer)
__device__ __forceinline__ void exp4(float& a, float& b, float& c, float& d) {
    asm("v_exp_f32 %0, %0\n\t"
        "v_exp_f32 %1, %1\n\t"
        "v_exp_f32 %2, %2\n\t"
        "v_exp_f32 %3, %3\n\t"
        "s_nop 1"
        : "+v"(a), "+v"(b), "+v"(c), "+v"(d));
}
// pack 2 f32 -> 2 bf16 (RNE), lo in low 16 bits
__device__ __forceinline__ u32 cvtpk(float lo, float hi) {
    u32 r;
    asm("v_cvt_pk_bf16_f32 %0, %1, %2" : "=v"(r) : "v"(lo), "v"(hi));
    return r;
}

// ---------- kernel 1: fp32 -> bf16 cast ----------
__global__ __launch_bounds__(256) void cast_kernel(const float* __restrict__ in,
                                                   u16* __restrict__ out, int n) {
    int i = (blockIdx.x * 256 + threadIdx.x) * 8;
    if (i >= n) return;
    float4 a = *(const float4*)(in + i);
    float4 b = *(const float4*)(in + i + 4);
    u32x4 r;
    r.x = (u32)f2bf(a.x) | ((u32)f2bf(a.y) << 16);
    r.y = (u32)f2bf(a.z) | ((u32)f2bf(a.w) << 16);
    r.z = (u32)f2bf(b.x) | ((u32)f2bf(b.y) << 16);
    r.w = (u32)f2bf(b.z) | ((u32)f2bf(b.w) << 16);
    *(u32x4*)(out + i) = r;
}

// ---------- kernels 2 & 4: NT GEMM  C[m][o] = sum_k A[m][k]*B[o][k] ----------
// MODE 0: Q (pre-scaled by 0.125*log2e) / K into [pair][n][64], V transposed
//         into VT [pair][64][2048]. MODE 1: +bias, fp32 out.
template <int MODE>
__global__ __launch_bounds__(256) void gemm_bt(
    const u16* __restrict__ A, const u16* __restrict__ B, int K, int N,
    u16* __restrict__ qo, u16* __restrict__ ko, u16* __restrict__ vto,
    float* __restrict__ fo, const float* __restrict__ bias)
{
    __shared__ __align__(16) u16 Al[128][72];
    __shared__ __align__(16) u16 Bl[128][72];
    const int t = threadIdx.x;
    const int w = t >> 6, l = t & 63;
    const int wr = w >> 1, wc = w & 1;
    const int g = l >> 4, li = l & 15;
    const int m0 = blockIdx.x * 128, n0 = blockIdx.y * 128;

    const f32x4 z = {0.f, 0.f, 0.f, 0.f};
    f32x4 acc[4][4];
#pragma unroll
    for (int mi = 0; mi < 4; ++mi)
#pragma unroll
        for (int ni = 0; ni < 4; ++ni) acc[mi][ni] = z;

    const int srow = t >> 3, sch = (t & 7) * 8;
    for (int k0 = 0; k0 < K; k0 += 64) {
        __syncthreads();
#pragma unroll
        for (int rnd = 0; rnd < 4; ++rnd) {
            int row = srow + rnd * 32;
            u32x4 av = *(const u32x4*)(A + (size_t)(m0 + row) * K + k0 + sch);
            u32x4 bv = *(const u32x4*)(B + (size_t)(n0 + row) * K + k0 + sch);
            *(u32x4*)&Al[row][sch] = av;
            *(u32x4*)&Bl[row][sch] = bv;
        }
        __syncthreads();
#pragma unroll
        for (int ks = 0; ks < 2; ++ks) {
            u32x4 af[4], bf[4];
#pragma unroll
            for (int mi = 0; mi < 4; ++mi)
                af[mi] = *(const u32x4*)&Al[wr * 64 + mi * 16 + li][ks * 32 + g * 8];
#pragma unroll
            for (int ni = 0; ni < 4; ++ni)
                bf[ni] = *(const u32x4*)&Bl[wc * 64 + ni * 16 + li][ks * 32 + g * 8];
#pragma unroll
            for (int mi = 0; mi < 4; ++mi)
#pragma unroll
                for (int ni = 0; ni < 4; ++ni) mfma16(acc[mi][ni], af[mi], bf[ni]);
        }
    }

#pragma unroll
    for (int mi = 0; mi < 4; ++mi) {
#pragma unroll
        for (int ni = 0; ni < 4; ++ni) {
            int o = n0 + wc * 64 + ni * 16 + li;
            int m_base = m0 + wr * 64 + mi * 16 + g * 4;
            if (MODE == 0) {
                int part = o >> 9, oi = o & 511;
                int h = oi >> 6, d = oi & 63;
                int bb = m_base >> 11, nn = m_base & 2047;
                if (part == 2) {
                    u32x2 pv;
                    pv.x = (u32)f2bf(acc[mi][ni][0]) | ((u32)f2bf(acc[mi][ni][1]) << 16);
                    pv.y = (u32)f2bf(acc[mi][ni][2]) | ((u32)f2bf(acc[mi][ni][3]) << 16);
                    *(u32x2*)(vto + ((size_t)(bb * 8 + h) * 64 + d) * 2048 + nn) = pv;
                } else {
                    u16* dst = (part == 0) ? qo : ko;
                    const float sc = (part == 0) ? 0.18033688011112042f : 1.0f;
#pragma unroll
                    for (int r = 0; r < 4; ++r)
                        dst[((size_t)(bb * 8 + h) * 2048 + nn + r) * 64 + d] =
                            f2bf(acc[mi][ni][r] * sc);
                }
            } else {
#pragma unroll
                for (int r = 0; r < 4; ++r)
                    fo[(size_t)(m_base + r) * N + o] = acc[mi][ni][r] + bias[o];
            }
        }
    }
}

// ---------- kernel 3: flash attention ----------
// 128 threads (2 waves), each wave 64 q-rows (qb=4). KV tiles of 64.
// PROVEN round-2 sync staging: barrier -> stage -> barrier -> compute.
// Swapped QK^T with bit-permuted K rows -> in-register softmax, P packs
// directly into PV B-fragments. Q pre-scaled into exp2 domain.
__global__ __launch_bounds__(128, 1) void attn_kernel(
    const u16* __restrict__ Q, const u16* __restrict__ Kg,
    const u16* __restrict__ VT, u16* __restrict__ O)
{
    __shared__ __align__(16) u16 Kl[64 * 64];   // row p: K row kperm(p), XOR-swizzled
    __shared__ __align__(16) u16 Vl[64 * 64];   // row d: V^T row d,      XOR-swizzled
    const int t = threadIdx.x;
    const int w = t >> 6, l = t & 63;
    const int g = l >> 4, li = l & 15;
    const int pair = blockIdx.y;
    const int q0 = blockIdx.x * 128 + w * 64;

    // Q as B-fragments: qf[qb][f] = Q[q0+qb*16+li][f*32+8g..+7]
    u32x4 qf[4][2];
#pragma unroll
    for (int qb = 0; qb < 4; ++qb)
#pragma unroll
        for (int f = 0; f < 2; ++f)
            qf[qb][f] = *(const u32x4*)(Q + ((size_t)pair * 2048 + q0 + qb * 16 + li) * 64
                                          + f * 32 + g * 8);

    const f32x4 z = {0.f, 0.f, 0.f, 0.f};
    f32x4 oacc[4][4];                       // [qb][dc] O^T accumulators
#pragma unroll
    for (int qb = 0; qb < 4; ++qb)
#pragma unroll
        for (int dc = 0; dc < 4; ++dc) oacc[qb][dc] = z;
    float m_r[4] = {-1e30f, -1e30f, -1e30f, -1e30f};
    float l_r[4] = {0.f, 0.f, 0.f, 0.f};

    const u16* kbase = Kg + (size_t)pair * 2048 * 64;
    const u16* vbase = VT + (size_t)pair * 64 * 2048;

    for (int kt = 0; kt < 32; ++kt) {
        __syncthreads();   // protect previous tile's reads
#pragma unroll
        for (int i = 0; i < 4; ++i) {
            int s = i * 128 + t;
            int p = s >> 3, cp = s & 7;
            int cg = (cp ^ (p & 7)) * 8;                              // XOR swizzle
            int kr = (p & 0x23) | ((p & 0x0C) << 1) | ((p & 0x10) >> 2);  // row bit-perm
            *(u32x4*)&Kl[p * 64 + cp * 8] =
                *(const u32x4*)(kbase + (size_t)kt * 4096 + kr * 64 + cg);
            *(u32x4*)&Vl[p * 64 + cp * 8] =
                *(const u32x4*)(vbase + (size_t)p * 2048 + kt * 64 + cg);
        }
        __syncthreads();

        // S^T = K x Q^T : st[qb][kc][r] is k = 32*(kc>>1)+8g+4*(kc&1)+r, q = q0+qb*16+li
        f32x4 st[4][4];
#pragma unroll
        for (int qb = 0; qb < 4; ++qb)
#pragma unroll
            for (int kc = 0; kc < 4; ++kc) st[qb][kc] = z;
#pragma unroll
        for (int kc = 0; kc < 4; ++kc)
#pragma unroll
            for (int f = 0; f < 2; ++f) {
                u32x4 kf = *(const u32x4*)&Kl[(kc * 16 + li) * 64
                                              + (((4 * f + g) ^ (li & 7)) * 8)];
#pragma unroll
                for (int qb = 0; qb < 4; ++qb) mfma16(st[qb][kc], kf, qf[qb][f]);
            }

        // in-register online softmax (exp2 domain) + bf16 pack
        u32x4 pb[4][2];
#pragma unroll
        for (int qb = 0; qb < 4; ++qb) {
            float a0 = fmaxf(fmaxf(st[qb][0][0], st[qb][0][1]), fmaxf(st[qb][0][2], st[qb][0][3]));
            float a1 = fmaxf(fmaxf(st[qb][1][0], st[qb][1][1]), fmaxf(st[qb][1][2], st[qb][1][3]));
            float a2 = fmaxf(fmaxf(st[qb][2][0], st[qb][2][1]), fmaxf(st[qb][2][2], st[qb][2][3]));
            float a3 = fmaxf(fmaxf(st[qb][3][0], st[qb][3][1]), fmaxf(st[qb][3][2], st[qb][3][3]));
            float tmax = fmaxf(fmaxf(a0, a1), fmaxf(a2, a3));
            if (__any(tmax - m_r[qb] > 11.0f)) {       // effectively tile 0 only
                float m4 = tmax;
                m4 = fmaxf(m4, __shfl_xor(m4, 16));
                m4 = fmaxf(m4, __shfl_xor(m4, 32));
                float mn = fmaxf(m_r[qb], m4);
                float alpha = exp2a(m_r[qb] - mn);
                m_r[qb] = mn;
                l_r[qb] *= alpha;
#pragma unroll
                for (int dc = 0; dc < 4; ++dc) oacc[qb][dc] *= alpha;
            }
            float nm = -m_r[qb];
            float pv[16];
#pragma unroll
            for (int kc = 0; kc < 4; ++kc) {
#pragma unroll
                for (int r = 0; r < 4; ++r) pv[kc * 4 + r] = st[qb][kc][r] + nm;
            }
            exp4(pv[0], pv[1], pv[2], pv[3]);
            exp4(pv[4], pv[5], pv[6], pv[7]);
            exp4(pv[8], pv[9], pv[10], pv[11]);
            exp4(pv[12], pv[13], pv[14], pv[15]);
            float s0 = (pv[0] + pv[1]) + (pv[2] + pv[3]);
            float s1 = (pv[4] + pv[5]) + (pv[6] + pv[7]);
            float s2 = (pv[8] + pv[9]) + (pv[10] + pv[11]);
            float s3 = (pv[12] + pv[13]) + (pv[14] + pv[15]);
            l_r[qb] += (s0 + s1) + (s2 + s3);
#pragma unroll
            for (int f = 0; f < 2; ++f) {
                u32x4 pk;
                pk.x = cvtpk(pv[8 * f + 0], pv[8 * f + 1]);
                pk.y = cvtpk(pv[8 * f + 2], pv[8 * f + 3]);
                pk.z = cvtpk(pv[8 * f + 4], pv[8 * f + 5]);
                pk.w = cvtpk(pv[8 * f + 6], pv[8 * f + 7]);
                pb[qb][f] = pk;
            }
        }

        // O^T += V^T x P^T
#pragma unroll
        for (int dc = 0; dc < 4; ++dc)
#pragma unroll
            for (int f = 0; f < 2; ++f) {
                u32x4 vf = *(const u32x4*)&Vl[(dc * 16 + li) * 64
                                              + (((4 * f + g) ^ (li & 7)) * 8)];
#pragma unroll
                for (int qb = 0; qb < 4; ++qb) mfma16(oacc[qb][dc], vf, pb[qb][f]);
            }
    }

    // epilogue: lane holds O^T[dc*16+4g+r][q0+qb*16+li]
    const int bb = pair >> 3, h = pair & 7;
#pragma unroll
    for (int qb = 0; qb < 4; ++qb) {
        float ls = l_r[qb];
        ls += __shfl_xor(ls, 16);
        ls += __shfl_xor(ls, 32);
        float inv = 1.f / ls;
        u16* orow = O + ((size_t)bb * 2048 + q0 + qb * 16 + li) * 512 + h * 64;
#pragma unroll
        for (int dc = 0; dc < 4; ++dc) {
            u32x2 pv;
            pv.x = cvtpk(oacc[qb][dc][0] * inv, oacc[qb][dc][1] * inv);
            pv.y = cvtpk(oacc[qb][dc][2] * inv, oacc[qb][dc][3] * inv);
            *(u32x2*)(orow + dc * 16 + 4 * g) = pv;
        }
    }
}

// ---------- launcher ----------
extern "C" void kernel_launch(void* const* d_in, const int* in_sizes, int n_in,
                              void* d_out, int out_size, void* d_ws, size_t ws_size,
                              hipStream_t stream) {
    const float* x     = (const float*)d_in[0];   // [4,2048,512]
    const float* w_qkv = (const float*)d_in[1];   // [1536,512]
    const float* w_out = (const float*)d_in[2];   // [512,512]
    const float* b_out = (const float*)d_in[3];   // [512]
    float* out = (float*)d_out;                   // [4,2048,512] fp32

    char* ws = (char*)d_ws;
    u16* xb = (u16*)(ws + 0);           // 8 MiB   (dead after QKV GEMM)
    u16* o  = (u16*)(ws + 0);           // reuse:  O [8192][512]
    u16* wq = (u16*)(ws + 8388608);     // 1.5 MiB
    u16* wo = (u16*)(ws + 9961472);     // 0.5 MiB
    u16* q  = (u16*)(ws + 10485760);    // 8 MiB   Q  [32][2048][64] (pre-scaled)
    u16* kk = (u16*)(ws + 18874368);    // 8 MiB   K  [32][2048][64]
    u16* vt = (u16*)(ws + 27262976);    // 8 MiB   VT [32][64][2048]

    cast_kernel<<<2048, 256, 0, stream>>>(x, xb, 4194304);
    cast_kernel<<<384, 256, 0, stream>>>(w_qkv, wq, 786432);
    cast_kernel<<<128, 256, 0, stream>>>(w_out, wo, 262144);

    // qkv = x @ w_qkv.T  (M=8192, N=1536, K=512) -> Q(scaled), K, VT
    gemm_bt<0><<<dim3(64, 12), 256, 0, stream>>>(xb, wq, 512, 1536,
                                                 q, kk, vt, nullptr, nullptr);
    attn_kernel<<<dim3(16, 32), 128, 0, stream>>>(q, kk, vt, o);

    // out = O @ w_out.T + b_out  (M=8192, N=512, K=512)
    gemm_bt<1><<<dim3(64, 4), 256, 0, stream>>>(o, wo, 512, 512,
                                                nullptr, nullptr, nullptr, out, b_out);
}